// Round 7
// baseline (283.019 us; speedup 1.0000x reference)
//
#include <hip/hip_runtime.h>
#include <hip/hip_bf16.h>

typedef __attribute__((ext_vector_type(8)))  short bf16x8;   // 8 bf16 = 4 VGPRs
typedef __attribute__((ext_vector_type(16))) float f32x16;   // 32x32 MFMA accumulator

constexpr int Bn = 32, Cn = 64, Hn = 64, Wn = 256, On = 64, En = 4, Rn = 4;
constexpr float SCALE = 1.0f / Rn;

// packed-x geometry (round-1-verified layout): per (b,h) row, 258 slots x 128B,
// slot s holds c=0..63 of x[b][:][h][s-1], c-group cb at byte ((cb^(s&7))*16),
// slots 0 and 257 are zero (SAME-padding halo).
constexpr int ROW_B  = 258 * 128;   // 33024 B per packed row

constexpr int WTILE  = 64;          // w per conv block
constexpr int HSTRIP = 8;           // output rows per conv block
constexpr int SLOT_B = 66 * 128;    // 8448 B conv ring slot (= window: slots w0..w0+65)

constexpr size_t WFRAG_B = 294912;
constexpr size_t XP_B    = (size_t)Bn * Hn * ROW_B;   // 67,633,152
constexpr size_t ZROW_B  = ROW_B;                     // zero row for h-OOB

#define GLOAD_LDS16(SRC, DST) \
    __builtin_amdgcn_global_load_lds( \
        (const __attribute__((address_space(1))) void*)(SRC), \
        (__attribute__((address_space(3))) void*)(DST), 16, 0, 0)

// ---------------------------------------------------------------------------
// Merge LoRA into conv weights, in 32x32x16 A-fragment order (unchanged):
// Wfrag[e][mh][s][lane][j]:  o = mh*32 + (lane&31),
//   k: tap = s>>2, c = (s&3)*16 + (lane>>5)*8 + j
// ---------------------------------------------------------------------------
__global__ __launch_bounds__(256) void merge_k(
    const float* __restrict__ Wc, const float* __restrict__ Wa,
    const float* __restrict__ Wb, __hip_bfloat16* __restrict__ Wfrag)
{
    int t = blockIdx.x * 256 + threadIdx.x;          // 0..147455 exact
    int j    = t & 7;
    int lane = (t >> 3) & 63;
    int g    = t >> 9;                               // (e*2+mh)*36 + s
    int s    = g % 36;
    int mh   = (g / 36) & 1;
    int e    = g / 72;
    int m = lane & 31, half = lane >> 5;
    int o = mh * 32 + m;
    int tap = s >> 2, cq = s & 3;
    int c = cq * 16 + half * 8 + j;
    float acc = Wc[(o * Cn + c) * 9 + tap];
#pragma unroll
    for (int r = 0; r < Rn; ++r)
        acc += SCALE * Wb[(e * On + o) * Rn + r] * Wa[((e * Rn + r) * Cn + c) * 9 + tap];
    Wfrag[t] = __float2bfloat16(acc);
}

// ---------------------------------------------------------------------------
// Pack pass (round-1-verified): x fp32 NCHW -> xp bf16 ring-image rows.
// Extra tail blocks zero the shared h-OOB zero-row.
// ---------------------------------------------------------------------------
__global__ __launch_bounds__(256) void pack_k(
    const float* __restrict__ x, __hip_bfloat16* __restrict__ xp,
    __hip_bfloat16* __restrict__ zr)
{
    size_t g = (size_t)blockIdx.x * 256 + threadIdx.x;
    if (blockIdx.x < 8192) {
        int l  = (int)(g & 1023);
        int cb = l & 7;
        int p  = l >> 3;                 // 0..127
        int bh = (int)(g >> 10);         // b*64 + h, 0..2047
        const float* xr = x + ((size_t)(bh >> 6) * Cn * Hn + (bh & 63)) * Wn;
        union { __hip_bfloat16 u[8]; bf16x8 v; } u0, u1;
#pragma unroll
        for (int i = 0; i < 8; ++i) {
            int c = cb * 8 + i;
            float2 L = *reinterpret_cast<const float2*>(xr + (size_t)c * Hn * Wn + 2 * p);
            u0.u[i] = __float2bfloat16(L.x);
            u1.u[i] = __float2bfloat16(L.y);
        }
        char* row = (char*)xp + (size_t)bh * ROW_B;
        int s0 = 2 * p + 1, s1 = 2 * p + 2;
        *reinterpret_cast<bf16x8*>(row + s0 * 128 + ((cb ^ (s0 & 7)) * 16)) = u0.v;
        *reinterpret_cast<bf16x8*>(row + s1 * 128 + ((cb ^ (s1 & 7)) * 16)) = u1.v;
    } else if (blockIdx.x < 8192 + 128) {
        int z = (int)(g - (size_t)8192 * 256);       // 0..32767
        int cb = z & 7, t = (z >> 3) & 1, bh = z >> 4;
        char* row = (char*)xp + (size_t)bh * ROW_B;
        bf16x8 zz = {};
        *reinterpret_cast<bf16x8*>(row + (t ? 257 : 0) * 128 + cb * 16) = zz;
    } else {
        int t = (int)(g - (size_t)(8192 + 128) * 256);
        if (t < ROW_B / 16) {
            bf16x8 zz = {};
            reinterpret_cast<bf16x8*>(zr)[t] = zz;
        }
    }
}

// ---------------------------------------------------------------------------
// Fused conv, v9 (m97-structure): staging = pure global_load_lds DMA.
// 256 threads, 4 waves (2mh x 2nh), WTILE=64, 4-slot ring.
// Per row: 3 x 4096B issues (3rd overlaps: src/dst +4352 covers the 256B tail
// with a benign 3840B duplicate write). No staging regs, no cvt, no ds_write.
// h-OOB rows -> shared zero-row via branch-free pointer select.
// Read swizzle = (ww&7): conflict-free for 8-lane ds_read_b128 phasing.
// Two accumulator chains halve the MFMA dependency depth.
// ---------------------------------------------------------------------------
__global__ __launch_bounds__(256, 2) void conv9_k(
    const __hip_bfloat16* __restrict__ xp, const __hip_bfloat16* __restrict__ zr,
    const int* __restrict__ sid, const __hip_bfloat16* __restrict__ Wfrag,
    float* __restrict__ out)
{
    __shared__ __align__(16) char xs[4 * SLOT_B];        // 33792 B ring

    const int tid = threadIdx.x;
    const int w0  = blockIdx.x * WTILE;
    const int h0  = blockIdx.y * HSTRIP;
    const int b   = blockIdx.z;
    const int e   = sid[b];
    const size_t HW = (size_t)Hn * Wn;

    const int lane = tid & 63, wave = tid >> 6;
    const int mh = wave & 1, nh = wave >> 1;
    const int n = lane & 31, half = lane >> 5;

    // A fragments: 36 x bf16x8, loaded once (L2-resident), live in VGPRs/AGPRs.
    bf16x8 wf[36];
    const bf16x8* wg = reinterpret_cast<const bf16x8*>(Wfrag) + (size_t)(e * 2 + mh) * 36 * 64;
#pragma unroll
    for (int s = 0; s < 36; ++s) wf[s] = wg[s * 64 + lane];

    // window of packed row (b,gh) for this w-tile: slots w0..w0+65, contiguous
    const char* xpb = (const char*)xp + (size_t)b * Hn * ROW_B + (size_t)w0 * 128;
    const char* zrw = (const char*)zr + (size_t)w0 * 128;
    const int lofs = wave * 1024 + lane * 16;            // per-lane source offset

    auto stage = [&](int rx) {
        const int gh = h0 + rx;
        const char* src = ((unsigned)gh < (unsigned)Hn) ? (xpb + (size_t)gh * ROW_B) : zrw;
        char* dst = xs + ((rx + 1) & 3) * SLOT_B + wave * 1024;   // wave-uniform dest
        GLOAD_LDS16(src + lofs,        dst);
        GLOAD_LDS16(src + 4096 + lofs, dst + 4096);
        GLOAD_LDS16(src + 4352 + lofs, dst + 4352);   // tail via overlap
    };

    // prologue: x rows h0-1, h0, h0+1 -> slots 0,1,2
    stage(-1); stage(0); stage(1);
    __syncthreads();

    for (int st = 0; st < HSTRIP; ++st) {
        // 1. DMA next row (slot (st+3)&3; readers finished last iteration)
        stage(st + 2);

        // 2. compute output row h0+st (two independent acc chains)
        f32x16 a0, a1;
#pragma unroll
        for (int i = 0; i < 16; ++i) { a0[i] = 0.0f; a1[i] = 0.0f; }

#pragma unroll
        for (int s2 = 0; s2 < 18; ++s2) {
            {
                const int s = 2 * s2;
                const int tap = s >> 2, cq = s & 3;
                const int dh = tap / 3, dw = tap % 3;
                int ww = nh * 32 + n + dw;               // 0..65
                const char* p = xs + ((st + dh) & 3) * SLOT_B
                              + ww * 128 + (((cq * 2 + half) ^ (ww & 7)) * 16);
                a0 = __builtin_amdgcn_mfma_f32_32x32x16_bf16(
                        wf[s], *reinterpret_cast<const bf16x8*>(p), a0, 0, 0, 0);
            }
            {
                const int s = 2 * s2 + 1;
                const int tap = s >> 2, cq = s & 3;
                const int dh = tap / 3, dw = tap % 3;
                int ww = nh * 32 + n + dw;
                const char* p = xs + ((st + dh) & 3) * SLOT_B
                              + ww * 128 + (((cq * 2 + half) ^ (ww & 7)) * 16);
                a1 = __builtin_amdgcn_mfma_f32_32x32x16_bf16(
                        wf[s], *reinterpret_cast<const bf16x8*>(p), a1, 0, 0, 0);
            }
        }

        // 3. epilogue: direct global stores; lanes n=0..31 cover 128B contiguous
        //    at (o = mh*32 + 4*half + (r&3)+8*(r>>2), row hrow).
        {
            const int hrow = h0 + st;
            size_t base = ((size_t)(b * On + mh * 32 + 4 * half) * Hn + hrow) * Wn
                          + w0 + nh * 32 + n;
#pragma unroll
            for (int r = 0; r < 16; ++r) {
                int o_off = (r & 3) + 8 * (r >> 2);
                out[base + (size_t)o_off * HW] = a0[r] + a1[r];
            }
        }

        // 4. publish DMA'd row / protect ring reuse (m97-style full sync)
        __syncthreads();
    }
}

// ---------------------------------------------------------------------------
// Fallback (ws too small): round-6 kernel verbatim (reg-staged, 101us).
// ---------------------------------------------------------------------------
constexpr int FB_WTILE  = 32;
constexpr int FB_HSTRIP = 16;
constexpr int FB_SLOT_B = 34 * 128;

__device__ __forceinline__ int fb_swz(int ww, int cb) {
    return ww * 128 + ((cb ^ ((ww >> 2) & 7)) * 16);
}

__global__ __launch_bounds__(128, 2) void conv8_k(
    const float* __restrict__ x, const int* __restrict__ sid,
    const __hip_bfloat16* __restrict__ Wfrag, float* __restrict__ out)
{
    __shared__ __align__(16) char xs[4 * FB_SLOT_B];

    const int tid = threadIdx.x;
    const int w0  = blockIdx.x * FB_WTILE;
    const int h0  = blockIdx.y * FB_HSTRIP;
    const int b   = blockIdx.z;
    const int e   = sid[b];
    const size_t HW = (size_t)Hn * Wn;

    const int lane = tid & 63, mh = tid >> 6;
    const int n = lane & 31, half = lane >> 5;

    bf16x8 wf[36];
    const bf16x8* wg = reinterpret_cast<const bf16x8*>(Wfrag) + (size_t)(e * 2 + mh) * 36 * 64;
#pragma unroll
    for (int s = 0; s < 36; ++s) wf[s] = wg[s * 64 + lane];

    const int pb = tid >> 3, q = tid & 7;
    const float* xbase = x + ((size_t)b * Cn + pb * 4) * HW + w0 + 4 * q;

    const int hside = tid >> 6, hc = tid & 63;
    const int gwh   = hside ? (w0 + FB_WTILE) : (w0 - 1);
    const bool hv   = (unsigned)gwh < (unsigned)Wn;
    const float* hbase = x + ((size_t)b * Cn + hc) * HW + gwh;

    auto stage_load = [&](float4 (&f)[4], float& hx, int rx) {
        const int gh = h0 + rx;
        if ((unsigned)gh < (unsigned)Hn) {
            const float* src = xbase + (size_t)gh * Wn;
#pragma unroll
            for (int r = 0; r < 4; ++r)
                f[r] = *reinterpret_cast<const float4*>(src + r * HW);
            hx = hv ? hbase[(size_t)gh * Wn] : 0.0f;
        } else {
            float4 z4 = make_float4(0.0f, 0.0f, 0.0f, 0.0f);
#pragma unroll
            for (int r = 0; r < 4; ++r) f[r] = z4;
            hx = 0.0f;
        }
    };
    auto stage_store = [&](float4 (&f)[4], float& hx, int rx) {
        const int slot = (rx + 1) & 3;
        char* dbase = xs + slot * FB_SLOT_B;
        const int cb = pb >> 1, sub = (pb & 1) * 8;
#pragma unroll
        for (int j = 0; j < 4; ++j) {
            union { __hip_bfloat16 u[4]; short4 v; } pk;
#pragma unroll
            for (int r = 0; r < 4; ++r) {
                float v = (j == 0) ? f[r].x : (j == 1) ? f[r].y : (j == 2) ? f[r].z : f[r].w;
                pk.u[r] = __float2bfloat16(v);
            }
            int ww = 4 * q + 1 + j;
            *reinterpret_cast<short4*>(dbase + fb_swz(ww, cb) + sub) = pk.v;
        }
        {
            __hip_bfloat16 hb = __float2bfloat16(hx);
            int ww = hside ? (FB_WTILE + 1) : 0;
            *reinterpret_cast<__hip_bfloat16*>(dbase + fb_swz(ww, hc >> 3) + (hc & 7) * 2) = hb;
        }
    };

    auto barrier = [&]() {
        asm volatile("s_waitcnt lgkmcnt(0)" ::: "memory");
        __builtin_amdgcn_s_barrier();
    };

    float4 fA[4], fB[4];
    float  hxA, hxB;

    stage_load(fA, hxA, -1); stage_store(fA, hxA, -1);
    stage_load(fA, hxA, 0);  stage_store(fA, hxA, 0);
    stage_load(fA, hxA, 1);  stage_store(fA, hxA, 1);
    stage_load(fA, hxA, 2);
    barrier();

    for (int st = 0; st < FB_HSTRIP; ++st) {
        const bool do_issue = (st + 3 <= FB_HSTRIP);
        if (do_issue) {
            if (st & 1) stage_load(fA, hxA, st + 3);
            else        stage_load(fB, hxB, st + 3);
        }

        f32x16 a;
#pragma unroll
        for (int i = 0; i < 16; ++i) a[i] = 0.0f;

#pragma unroll
        for (int s = 0; s < 36; ++s) {
            const int tap = s >> 2, cq = s & 3;
            const int dh = tap / 3, dw = tap % 3;
            const int slotbase = ((st + dh) & 3) * FB_SLOT_B;
            int ww = n + dw;
            bf16x8 bf = *reinterpret_cast<const bf16x8*>(xs + slotbase + fb_swz(ww, cq * 2 + half));
            a = __builtin_amdgcn_mfma_f32_32x32x16_bf16(wf[s], bf, a, 0, 0, 0);
        }

        const bool do_store = (st + 2 <= FB_HSTRIP);
        if (do_store) {
            if (st & 1) stage_store(fB, hxB, st + 2);
            else        stage_store(fA, hxA, st + 2);
        }

        {
            const int hrow = h0 + st;
            size_t base = ((size_t)(b * On + mh * 32 + 4 * half) * Hn + hrow) * Wn + w0 + n;
#pragma unroll
            for (int r = 0; r < 16; ++r) {
                int o_off = (r & 3) + 8 * (r >> 2);
                out[base + (size_t)o_off * HW] = a[r];
            }
        }

        barrier();
    }
}

// ---------------------------------------------------------------------------
extern "C" void kernel_launch(void* const* d_in, const int* in_sizes, int n_in,
                              void* d_out, int out_size, void* d_ws, size_t ws_size,
                              hipStream_t stream)
{
    const float* x   = (const float*)d_in[0];
    const int*   sid = (const int*)d_in[1];
    const float* Wc  = (const float*)d_in[2];
    const float* Wa  = (const float*)d_in[3];
    const float* Wb  = (const float*)d_in[4];
    float*       out = (float*)d_out;

    __hip_bfloat16* Wfrag = (__hip_bfloat16*)d_ws;

    merge_k<<<En * 2 * 36 * 64 * 8 / 256, 256, 0, stream>>>(Wc, Wa, Wb, Wfrag);

    const size_t NEED = WFRAG_B + XP_B + ZROW_B;   // 67,961,088
    if (ws_size >= NEED) {
        __hip_bfloat16* xp = (__hip_bfloat16*)((char*)d_ws + WFRAG_B);
        __hip_bfloat16* zw = (__hip_bfloat16*)((char*)d_ws + WFRAG_B + XP_B);
        pack_k<<<8192 + 128 + 9, 256, 0, stream>>>(x, xp, zw);
        dim3 grid(Wn / WTILE, Hn / HSTRIP, Bn);
        conv9_k<<<grid, 256, 0, stream>>>(xp, zw, sid, Wfrag, out);
    } else {
        dim3 grid(Wn / FB_WTILE, Hn / FB_HSTRIP, Bn);
        conv8_k<<<grid, 128, 0, stream>>>(x, sid, Wfrag, out);
    }
}

// Round 8
// 277.362 us; speedup vs baseline: 1.0204x; 1.0204x over previous
//
#include <hip/hip_runtime.h>
#include <hip/hip_bf16.h>

typedef __attribute__((ext_vector_type(8)))  short bf16x8;   // 8 bf16 = 4 VGPRs
typedef __attribute__((ext_vector_type(16))) float f32x16;   // 32x32 MFMA accumulator

constexpr int Bn = 32, Cn = 64, Hn = 64, Wn = 256, On = 64, En = 4, Rn = 4;
constexpr float SCALE = 1.0f / Rn;

// packed-x geometry (round-1/7-verified layout): per (b,h) row, 258 slots x 128B,
// slot s holds c=0..63 of x[b][:][h][s-1], c-group cb at byte ((cb^(s&7))*16),
// slots 0 and 257 are zero (SAME-padding halo).
constexpr int ROW_B  = 258 * 128;   // 33024 B per packed row

constexpr int WTILE  = 64;          // w per conv block
constexpr int HSTRIP = 8;           // output rows per conv block
constexpr int SLOT_B = 66 * 128;    // 8448 B conv ring slot (= window: slots w0..w0+65)

constexpr size_t WFRAG_B = 294912;
constexpr size_t XP_B    = (size_t)Bn * Hn * ROW_B;   // 67,633,152
constexpr size_t ZROW_B  = ROW_B;                     // zero row for h-OOB

#define GLOAD_LDS16(SRC, DST) \
    __builtin_amdgcn_global_load_lds( \
        (const __attribute__((address_space(1))) void*)(SRC), \
        (__attribute__((address_space(3))) void*)(DST), 16, 0, 0)

// ---------------------------------------------------------------------------
// Merge LoRA into conv weights, in 32x32x16 A-fragment order (unchanged):
// Wfrag[e][mh][s][lane][j]:  o = mh*32 + (lane&31),
//   k: tap = s>>2, c = (s&3)*16 + (lane>>5)*8 + j
// ---------------------------------------------------------------------------
__global__ __launch_bounds__(256) void merge_k(
    const float* __restrict__ Wc, const float* __restrict__ Wa,
    const float* __restrict__ Wb, __hip_bfloat16* __restrict__ Wfrag)
{
    int t = blockIdx.x * 256 + threadIdx.x;          // 0..147455 exact
    int j    = t & 7;
    int lane = (t >> 3) & 63;
    int g    = t >> 9;                               // (e*2+mh)*36 + s
    int s    = g % 36;
    int mh   = (g / 36) & 1;
    int e    = g / 72;
    int m = lane & 31, half = lane >> 5;
    int o = mh * 32 + m;
    int tap = s >> 2, cq = s & 3;
    int c = cq * 16 + half * 8 + j;
    float acc = Wc[(o * Cn + c) * 9 + tap];
#pragma unroll
    for (int r = 0; r < Rn; ++r)
        acc += SCALE * Wb[(e * On + o) * Rn + r] * Wa[((e * Rn + r) * Cn + c) * 9 + tap];
    Wfrag[t] = __float2bfloat16(acc);
}

// ---------------------------------------------------------------------------
// Pack pass v2: identical output bytes to the verified pack_k, restructured
// for coalescing. Team of 512 threads per (b,h) row; thread = (cb, wq):
//   loads 8 x float4 (c = cb*8+i, w = 4wq..4wq+3) -> 64B segments per 4 lanes
//   register-transpose -> 4 x 16B units (slots 4wq+1+j); per store inst a wave
//   covers 8 full 128B slots.
// Tail blocks: zero halo slots 0/257 and the shared h-OOB zero-row.
// ---------------------------------------------------------------------------
__global__ __launch_bounds__(256) void pack2_k(
    const float* __restrict__ x, __hip_bfloat16* __restrict__ xp,
    __hip_bfloat16* __restrict__ zr)
{
    const int blk = blockIdx.x;
    if (blk < 4096) {
        int l  = ((blk & 1) << 8) | threadIdx.x;     // 0..511 within row team
        int bh = blk >> 1;                           // b*64 + h
        int wLo = l & 3, cb = (l >> 2) & 7, wHi = l >> 5;
        int wq = wHi * 4 + wLo;                      // 0..63
        int b = bh >> 6, h = bh & 63;
        const float* src = x + (((size_t)(b * Cn + cb * 8) * Hn + h) * Wn) + 4 * wq;
        float4 f[8];
#pragma unroll
        for (int i = 0; i < 8; ++i)
            f[i] = *reinterpret_cast<const float4*>(src + (size_t)i * Hn * Wn);
        char* row = (char*)xp + (size_t)bh * ROW_B;
#pragma unroll
        for (int j = 0; j < 4; ++j) {
            union { __hip_bfloat16 u[8]; bf16x8 v; } pk;
#pragma unroll
            for (int i = 0; i < 8; ++i) {
                float v = (j == 0) ? f[i].x : (j == 1) ? f[i].y : (j == 2) ? f[i].z : f[i].w;
                pk.u[i] = __float2bfloat16(v);
            }
            int s = 4 * wq + 1 + j;                  // 1..256
            *reinterpret_cast<bf16x8*>(row + s * 128 + ((cb ^ (s & 7)) * 16)) = pk.v;
        }
    } else if (blk < 4096 + 128) {
        int z = (blk - 4096) * 256 + threadIdx.x;    // 0..32767
        int cb = z & 7, t = (z >> 3) & 1, bh = z >> 4;
        char* row = (char*)xp + (size_t)bh * ROW_B;
        bf16x8 zz = {};
        *reinterpret_cast<bf16x8*>(row + (t ? 257 : 0) * 128 + cb * 16) = zz;
    } else {
        int t = (blk - 4096 - 128) * 256 + threadIdx.x;
        if (t < ROW_B / 16) {
            bf16x8 zz = {};
            reinterpret_cast<bf16x8*>(zr)[t] = zz;
        }
    }
}

// ---------------------------------------------------------------------------
// Fused conv, v10 = v9 + counted-vmcnt barrier (T4) + XCD-chunked block swizzle.
// Per iteration a wave issues exactly 3 DMA (global_load_lds) then 16 out
// stores; the end-of-iteration barrier only needs the DMAs retired, so
//   s_waitcnt vmcnt(16) lgkmcnt(0); s_barrier
// leaves the stores in flight (in-order vmcnt retirement guarantees the 3
// older DMAs are done once outstanding <= 16). An empty memory-clobber asm
// after stage() pins DMA-before-stores so the count is exact.
// Induction: barrier(st-1) leaves <=16 outstanding (prev stores); iter st
// adds 3 DMA + 16 stores -> <=35; waiting to <=16 retires everything except
// the 16 newest = this iter's stores. QED.
// ---------------------------------------------------------------------------
__global__ __launch_bounds__(256, 2) void conv10_k(
    const __hip_bfloat16* __restrict__ xp, const __hip_bfloat16* __restrict__ zr,
    const int* __restrict__ sid, const __hip_bfloat16* __restrict__ Wfrag,
    float* __restrict__ out)
{
    __shared__ __align__(16) char xs[4 * SLOT_B];        // 33792 B ring

    // XCD-chunked bijective swizzle (1024 blocks, 1024%8==0): same-batch /
    // h-neighbor blocks (sharing xp halo rows) land on one XCD's L2.
    const int logical = ((blockIdx.x & 7) << 7) | (blockIdx.x >> 3);
    const int bx = logical & 3, by = (logical >> 2) & 7, b = logical >> 5;

    const int tid = threadIdx.x;
    const int w0  = bx * WTILE;
    const int h0  = by * HSTRIP;
    const int e   = sid[b];
    const size_t HW = (size_t)Hn * Wn;

    const int lane = tid & 63, wave = tid >> 6;
    const int mh = wave & 1, nh = wave >> 1;
    const int n = lane & 31, half = lane >> 5;

    // A fragments: 36 x bf16x8, loaded once (L2-resident), live in VGPRs/AGPRs.
    bf16x8 wf[36];
    const bf16x8* wg = reinterpret_cast<const bf16x8*>(Wfrag) + (size_t)(e * 2 + mh) * 36 * 64;
#pragma unroll
    for (int s = 0; s < 36; ++s) wf[s] = wg[s * 64 + lane];

    // window of packed row (b,gh) for this w-tile: slots w0..w0+65, contiguous
    const char* xpb = (const char*)xp + (size_t)b * Hn * ROW_B + (size_t)w0 * 128;
    const char* zrw = (const char*)zr + (size_t)w0 * 128;
    const int lofs = wave * 1024 + lane * 16;            // per-lane source offset

    auto stage = [&](int rx) {
        const int gh = h0 + rx;
        const char* src = ((unsigned)gh < (unsigned)Hn) ? (xpb + (size_t)gh * ROW_B) : zrw;
        char* dst = xs + ((rx + 1) & 3) * SLOT_B + wave * 1024;   // wave-uniform dest
        GLOAD_LDS16(src + lofs,        dst);
        GLOAD_LDS16(src + 4096 + lofs, dst + 4096);
        GLOAD_LDS16(src + 4352 + lofs, dst + 4352);   // tail via overlap
    };

    // prologue: x rows h0-1, h0, h0+1 -> slots 0,1,2 (full drain once)
    stage(-1); stage(0); stage(1);
    asm volatile("s_waitcnt vmcnt(0) lgkmcnt(0)" ::: "memory");
    __builtin_amdgcn_s_barrier();

    for (int st = 0; st < HSTRIP; ++st) {
        // 1. DMA next row (slot (st+3)&3; its readers finished last iteration)
        stage(st + 2);
        asm volatile("" ::: "memory");   // pin DMA issue before epilogue stores

        // 2. compute output row h0+st (two independent acc chains)
        f32x16 a0, a1;
#pragma unroll
        for (int i = 0; i < 16; ++i) { a0[i] = 0.0f; a1[i] = 0.0f; }

#pragma unroll
        for (int s2 = 0; s2 < 18; ++s2) {
            {
                const int s = 2 * s2;
                const int tap = s >> 2, cq = s & 3;
                const int dh = tap / 3, dw = tap % 3;
                int ww = nh * 32 + n + dw;               // 0..65
                const char* p = xs + ((st + dh) & 3) * SLOT_B
                              + ww * 128 + (((cq * 2 + half) ^ (ww & 7)) * 16);
                a0 = __builtin_amdgcn_mfma_f32_32x32x16_bf16(
                        wf[s], *reinterpret_cast<const bf16x8*>(p), a0, 0, 0, 0);
            }
            {
                const int s = 2 * s2 + 1;
                const int tap = s >> 2, cq = s & 3;
                const int dh = tap / 3, dw = tap % 3;
                int ww = nh * 32 + n + dw;
                const char* p = xs + ((st + dh) & 3) * SLOT_B
                              + ww * 128 + (((cq * 2 + half) ^ (ww & 7)) * 16);
                a1 = __builtin_amdgcn_mfma_f32_32x32x16_bf16(
                        wf[s], *reinterpret_cast<const bf16x8*>(p), a1, 0, 0, 0);
            }
        }

        // 3. epilogue: direct global stores; lanes n=0..31 cover 128B contiguous
        //    at (o = mh*32 + 4*half + (r&3)+8*(r>>2), row hrow).
        {
            const int hrow = h0 + st;
            size_t base = ((size_t)(b * On + mh * 32 + 4 * half) * Hn + hrow) * Wn
                          + w0 + nh * 32 + n;
#pragma unroll
            for (int r = 0; r < 16; ++r) {
                int o_off = (r & 3) + 8 * (r >> 2);
                out[base + (size_t)o_off * HW] = a0[r] + a1[r];
            }
        }

        // 4. counted-vmcnt barrier: wait only for this iter's 3 DMAs; the 16
        //    stores stay in flight across the barrier. lgkmcnt(0) protects the
        //    ds_reads of slot st&3 (overwritten by next iter's DMA).
        asm volatile("s_waitcnt vmcnt(16) lgkmcnt(0)" ::: "memory");
        __builtin_amdgcn_s_barrier();
    }
}

// ---------------------------------------------------------------------------
// Fallback (ws too small): round-6 kernel verbatim (reg-staged, 101us).
// ---------------------------------------------------------------------------
constexpr int FB_WTILE  = 32;
constexpr int FB_HSTRIP = 16;
constexpr int FB_SLOT_B = 34 * 128;

__device__ __forceinline__ int fb_swz(int ww, int cb) {
    return ww * 128 + ((cb ^ ((ww >> 2) & 7)) * 16);
}

__global__ __launch_bounds__(128, 2) void conv8_k(
    const float* __restrict__ x, const int* __restrict__ sid,
    const __hip_bfloat16* __restrict__ Wfrag, float* __restrict__ out)
{
    __shared__ __align__(16) char xs[4 * FB_SLOT_B];

    const int tid = threadIdx.x;
    const int w0  = blockIdx.x * FB_WTILE;
    const int h0  = blockIdx.y * FB_HSTRIP;
    const int b   = blockIdx.z;
    const int e   = sid[b];
    const size_t HW = (size_t)Hn * Wn;

    const int lane = tid & 63, mh = tid >> 6;
    const int n = lane & 31, half = lane >> 5;

    bf16x8 wf[36];
    const bf16x8* wg = reinterpret_cast<const bf16x8*>(Wfrag) + (size_t)(e * 2 + mh) * 36 * 64;
#pragma unroll
    for (int s = 0; s < 36; ++s) wf[s] = wg[s * 64 + lane];

    const int pb = tid >> 3, q = tid & 7;
    const float* xbase = x + ((size_t)b * Cn + pb * 4) * HW + w0 + 4 * q;

    const int hside = tid >> 6, hc = tid & 63;
    const int gwh   = hside ? (w0 + FB_WTILE) : (w0 - 1);
    const bool hv   = (unsigned)gwh < (unsigned)Wn;
    const float* hbase = x + ((size_t)b * Cn + hc) * HW + gwh;

    auto stage_load = [&](float4 (&f)[4], float& hx, int rx) {
        const int gh = h0 + rx;
        if ((unsigned)gh < (unsigned)Hn) {
            const float* src = xbase + (size_t)gh * Wn;
#pragma unroll
            for (int r = 0; r < 4; ++r)
                f[r] = *reinterpret_cast<const float4*>(src + r * HW);
            hx = hv ? hbase[(size_t)gh * Wn] : 0.0f;
        } else {
            float4 z4 = make_float4(0.0f, 0.0f, 0.0f, 0.0f);
#pragma unroll
            for (int r = 0; r < 4; ++r) f[r] = z4;
            hx = 0.0f;
        }
    };
    auto stage_store = [&](float4 (&f)[4], float& hx, int rx) {
        const int slot = (rx + 1) & 3;
        char* dbase = xs + slot * FB_SLOT_B;
        const int cb = pb >> 1, sub = (pb & 1) * 8;
#pragma unroll
        for (int j = 0; j < 4; ++j) {
            union { __hip_bfloat16 u[4]; short4 v; } pk;
#pragma unroll
            for (int r = 0; r < 4; ++r) {
                float v = (j == 0) ? f[r].x : (j == 1) ? f[r].y : (j == 2) ? f[r].z : f[r].w;
                pk.u[r] = __float2bfloat16(v);
            }
            int ww = 4 * q + 1 + j;
            *reinterpret_cast<short4*>(dbase + fb_swz(ww, cb) + sub) = pk.v;
        }
        {
            __hip_bfloat16 hb = __float2bfloat16(hx);
            int ww = hside ? (FB_WTILE + 1) : 0;
            *reinterpret_cast<__hip_bfloat16*>(dbase + fb_swz(ww, hc >> 3) + (hc & 7) * 2) = hb;
        }
    };

    auto barrier = [&]() {
        asm volatile("s_waitcnt lgkmcnt(0)" ::: "memory");
        __builtin_amdgcn_s_barrier();
    };

    float4 fA[4], fB[4];
    float  hxA, hxB;

    stage_load(fA, hxA, -1); stage_store(fA, hxA, -1);
    stage_load(fA, hxA, 0);  stage_store(fA, hxA, 0);
    stage_load(fA, hxA, 1);  stage_store(fA, hxA, 1);
    stage_load(fA, hxA, 2);
    barrier();

    for (int st = 0; st < FB_HSTRIP; ++st) {
        const bool do_issue = (st + 3 <= FB_HSTRIP);
        if (do_issue) {
            if (st & 1) stage_load(fA, hxA, st + 3);
            else        stage_load(fB, hxB, st + 3);
        }

        f32x16 a;
#pragma unroll
        for (int i = 0; i < 16; ++i) a[i] = 0.0f;

#pragma unroll
        for (int s = 0; s < 36; ++s) {
            const int tap = s >> 2, cq = s & 3;
            const int dh = tap / 3, dw = tap % 3;
            const int slotbase = ((st + dh) & 3) * FB_SLOT_B;
            int ww = n + dw;
            bf16x8 bf = *reinterpret_cast<const bf16x8*>(xs + slotbase + fb_swz(ww, cq * 2 + half));
            a = __builtin_amdgcn_mfma_f32_32x32x16_bf16(wf[s], bf, a, 0, 0, 0);
        }

        const bool do_store = (st + 2 <= FB_HSTRIP);
        if (do_store) {
            if (st & 1) stage_store(fB, hxB, st + 2);
            else        stage_store(fA, hxA, st + 2);
        }

        {
            const int hrow = h0 + st;
            size_t base = ((size_t)(b * On + mh * 32 + 4 * half) * Hn + hrow) * Wn + w0 + n;
#pragma unroll
            for (int r = 0; r < 16; ++r) {
                int o_off = (r & 3) + 8 * (r >> 2);
                out[base + (size_t)o_off * HW] = a[r];
            }
        }

        barrier();
    }
}

// ---------------------------------------------------------------------------
extern "C" void kernel_launch(void* const* d_in, const int* in_sizes, int n_in,
                              void* d_out, int out_size, void* d_ws, size_t ws_size,
                              hipStream_t stream)
{
    const float* x   = (const float*)d_in[0];
    const int*   sid = (const int*)d_in[1];
    const float* Wc  = (const float*)d_in[2];
    const float* Wa  = (const float*)d_in[3];
    const float* Wb  = (const float*)d_in[4];
    float*       out = (float*)d_out;

    __hip_bfloat16* Wfrag = (__hip_bfloat16*)d_ws;

    merge_k<<<En * 2 * 36 * 64 * 8 / 256, 256, 0, stream>>>(Wc, Wa, Wb, Wfrag);

    const size_t NEED = WFRAG_B + XP_B + ZROW_B;   // 67,961,088
    if (ws_size >= NEED) {
        __hip_bfloat16* xp = (__hip_bfloat16*)((char*)d_ws + WFRAG_B);
        __hip_bfloat16* zw = (__hip_bfloat16*)((char*)d_ws + WFRAG_B + XP_B);
        pack2_k<<<4096 + 128 + 9, 256, 0, stream>>>(x, xp, zw);
        conv10_k<<<dim3(1024, 1, 1), 256, 0, stream>>>(xp, zw, sid, Wfrag, out);
    } else {
        dim3 grid(Wn / FB_WTILE, Hn / FB_HSTRIP, Bn);
        conv8_k<<<grid, 128, 0, stream>>>(x, sid, Wfrag, out);
    }
}